// Round 1
// 261.657 us; speedup vs baseline: 1.0466x; 1.0466x over previous
//
#include <hip/hip_runtime.h>
#include <hip/hip_bf16.h>

#define TSEQ 2048
#define NHEAD 16
#define DM 1024
#define NBATCH 2
#define MTOK (NBATCH * TSEQ)   // 4096

typedef __attribute__((ext_vector_type(8))) short short8;
typedef __attribute__((ext_vector_type(4))) float floatx4;
typedef __attribute__((address_space(1))) const void gvoid;
typedef __attribute__((address_space(3))) void lvoid;

static __device__ __forceinline__ unsigned short f2bf(float f) {
    unsigned int u = __float_as_uint(f);
    return (unsigned short)((u + 0x7fffu + ((u >> 16) & 1u)) >> 16);
}
static __device__ __forceinline__ float bf2f(unsigned short h) {
    return __uint_as_float(((unsigned int)h) << 16);
}

// ---------------------------------------------------------------------------
// Pack x and the 6 weight matrices to split bf16 rows.
//   x      -> [hi(1024) | lo(1024)]
//   Wproj  -> [hi | lo]            (3-term proj GEMM needs lo)
//   Wq..Wv -> [hi | hi] DUPLICATED (qkv GEMM becomes one plain K=2048 GEMM:
//             [Ah|Al] . [Bh|Bh]^T == Ah.Bh^T + Al.Bh^T)
// blocks [0,4096) -> x ; [4096,10240) -> weights (1024 blocks each).
// ---------------------------------------------------------------------------
__global__ __launch_bounds__(256)
void pack_all_kernel(const float* __restrict__ x,
                     const float* __restrict__ w0, const float* __restrict__ w1,
                     const float* __restrict__ w2, const float* __restrict__ w3,
                     const float* __restrict__ w4, const float* __restrict__ w5,
                     unsigned short* __restrict__ dstX, unsigned short* __restrict__ dstW)
{
    const float* src;
    unsigned short* dst;
    int gid;
    bool dup = false;
    if (blockIdx.x < 4096) {
        src = x; dst = dstX;
        gid = blockIdx.x * 256 + threadIdx.x;
    } else {
        int wi = (blockIdx.x - 4096) >> 10;
        const float* srcs[6] = {w0, w1, w2, w3, w4, w5};
        src = srcs[wi];
        dst = dstW + (size_t)wi * 1024 * 2048;
        gid = ((blockIdx.x - 4096) & 1023) * 256 + threadIdx.x;
        dup = (wi != 0);
    }
    int e   = gid * 4;
    int row = e >> 10;
    int col = e & 1023;
    float4 f = *(const float4*)(src + (size_t)row * 1024 + col);
    ushort4 hi, lo;
    hi.x = f2bf(f.x); lo.x = f2bf(f.x - bf2f(hi.x));
    hi.y = f2bf(f.y); lo.y = f2bf(f.y - bf2f(hi.y));
    hi.z = f2bf(f.z); lo.z = f2bf(f.z - bf2f(hi.z));
    hi.w = f2bf(f.w); lo.w = f2bf(f.w - bf2f(hi.w));
    *(ushort4*)(dst + (size_t)row * 2048 + col)        = hi;
    *(ushort4*)(dst + (size_t)row * 2048 + 1024 + col) = dup ? hi : lo;
}

// ---------------------------------------------------------------------------
// qkv GEMM, 8-phase-style pipelined schedule (T3+T4+T5):
//   C[4096][5120] = Xp[4096][2048] . Bdup[5120][2048]^T   (plain bf16 GEMM)
// Tile 256x320, K-tile 64 split in two k-halves of 32, 512 threads = 8 waves,
// wave layout 8Mx1N (wave = 32 rows x 320 cols, frags 2x20, 160 acc VGPR).
// LDS 144KB: per parity {A_kh0[256][32], A_kh1, B_kh0[320][32], B_kh1}.
// One barrier per phase; counted vmcnt(8) at p2/p4 only (loads stay in
// flight across barriers); lgkmcnt(0) BEFORE each barrier so every region's
// last read drains >=1 full barrier before its overwrite is issued.
// Chunk-XOR swizzle (2-way, free) via pre-swizzled global source + linear
// global_load_lds dest (same scheme as previous kernel).
// Epilogue fuses RoPE + 1/64 q-scale, scatters heads + transposed V.
// Grid 16x16 = 256 blocks = exactly 1/CU (perfect balance; 320-wide N-tile
// chosen so grid is 256 and head groups stay wave-closed: 320 = 5*64).
// ---------------------------------------------------------------------------
#define VMW(N) asm volatile("s_waitcnt vmcnt(" #N ")" ::: "memory")
#define LGKM0  asm volatile("s_waitcnt lgkmcnt(0)" ::: "memory")

__global__ __launch_bounds__(512, 2)
void gemm_qkv(const unsigned short* __restrict__ Ap,
              const unsigned short* __restrict__ Bp,
              unsigned short* __restrict__ Ch, unsigned short* __restrict__ Vt)
{
    __shared__ __align__(16) unsigned short A0s[2][8192];    // [256][32] each
    __shared__ __align__(16) unsigned short A1s[2][8192];
    __shared__ __align__(16) unsigned short B0s[2][10240];   // [320][32] each
    __shared__ __align__(16) unsigned short B1s[2][10240];

    const int t    = threadIdx.x;
    const int lane = t & 63;
    const int w    = t >> 6;
    const int s    = lane & 15;
    const int g    = (lane >> 4) & 3;
    const int row0 = blockIdx.x * 256;
    const int col0 = blockIdx.y * 320;

    // read-side swizzled offsets (element units, 32-wide rows)
    const int cofs   = ((g ^ ((lane >> 1) & 3)) << 3);
    const int addrA0 = (w * 32 + 0 * 16 + s) * 32 + cofs;
    const int addrA1 = (w * 32 + 1 * 16 + s) * 32 + cofs;
    const int addrB  = s * 32 + cofs;

    // stage-side pre-swizzled global source base (logical chunk per thread)
    const int alc = (t & 3) ^ ((t >> 3) & 3);
    const unsigned short* Ag = Ap + (size_t)(row0 + (t >> 2)) * 2048 + alc * 8;
    const unsigned short* Bg = Bp + (size_t)(col0 + (t >> 2)) * 2048 + alc * 8;

#define STAGE_A(dst, kofs) {                                                                              \
    __builtin_amdgcn_global_load_lds((gvoid*)(Ag + (kofs)),              (lvoid*)((dst) + t * 8),        16, 0, 0); \
    __builtin_amdgcn_global_load_lds((gvoid*)(Ag + (kofs) + 128 * 2048), (lvoid*)((dst) + 4096 + t * 8), 16, 0, 0); }

#define STAGE_B(dst, kofs) {                                                                              \
    __builtin_amdgcn_global_load_lds((gvoid*)(Bg + (kofs)),              (lvoid*)((dst) + t * 8),        16, 0, 0); \
    __builtin_amdgcn_global_load_lds((gvoid*)(Bg + (kofs) + 128 * 2048), (lvoid*)((dst) + 4096 + t * 8), 16, 0, 0); \
    if (t < 256)                                                                                          \
    __builtin_amdgcn_global_load_lds((gvoid*)(Bg + (kofs) + 256 * 2048), (lvoid*)((dst) + 8192 + t * 8), 16, 0, 0); }

    floatx4 acc[2][20];
    #pragma unroll
    for (int m = 0; m < 2; ++m)
        #pragma unroll
        for (int nf = 0; nf < 20; ++nf)
            acc[m][nf] = (floatx4)(0.0f);

    // ---- prologue: tiles 0 (kh0,kh1) and 1 (kh0) ----
    STAGE_A(A0s[0], 0);
    STAGE_B(B0s[0], 0);
    STAGE_A(A1s[0], 32);
    STAGE_B(B1s[0], 32);
    STAGE_A(A0s[1], 64);
    STAGE_B(B0s[1], 64);
    VMW(4);                       // tile 0 fully landed (4 newest = tile1 kh0)
    __builtin_amdgcn_s_barrier();

#define TILE_BODY(TAU, DO12, DO34, W2, W4)                                                      \
{                                                                                               \
    const int cur_ = (TAU) & 1;                                                                 \
    const unsigned short* a0k = A0s[cur_];                                                      \
    const unsigned short* a1k = A1s[cur_];                                                      \
    const unsigned short* b0k = B0s[cur_];                                                      \
    const unsigned short* b1k = B1s[cur_];                                                      \
    short8 af0, af1;                                                                            \
    /* ---- p1: kstep0, nf 0-9 ; stage (TAU+1) A-kh1 ---- */                                    \
    {                                                                                           \
        af0 = *(const short8*)&a0k[addrA0];                                                     \
        af1 = *(const short8*)&a0k[addrA1];                                                     \
        short8 bf[10];                                                                          \
        _Pragma("unroll")                                                                       \
        for (int nf = 0; nf < 10; ++nf) bf[nf] = *(const short8*)&b0k[addrB + nf * 512];        \
        if (DO12) STAGE_A(A1s[cur_ ^ 1], ((TAU) + 1) * 64 + 32);                                \
        LGKM0;                                                                                  \
        __builtin_amdgcn_s_barrier();                                                           \
        __builtin_amdgcn_sched_barrier(0);                                                      \
        __builtin_amdgcn_s_setprio(1);                                                          \
        _Pragma("unroll")                                                                       \
        for (int nf = 0; nf < 10; ++nf) {                                                       \
            acc[0][nf] = __builtin_amdgcn_mfma_f32_16x16x32_bf16(af0, bf[nf], acc[0][nf], 0, 0, 0); \
            acc[1][nf] = __builtin_amdgcn_mfma_f32_16x16x32_bf16(af1, bf[nf], acc[1][nf], 0, 0, 0); \
        }                                                                                       \
        __builtin_amdgcn_s_setprio(0);                                                          \
    }                                                                                           \
    /* ---- p2: kstep0, nf 10-19 ; stage (TAU+1) B-kh1 ; vmcnt ---- */                          \
    {                                                                                           \
        short8 bf[10];                                                                          \
        _Pragma("unroll")                                                                       \
        for (int nf = 0; nf < 10; ++nf) bf[nf] = *(const short8*)&b0k[addrB + (nf + 10) * 512]; \
        if (DO12) STAGE_B(B1s[cur_ ^ 1], ((TAU) + 1) * 64 + 32);                                \
        LGKM0;                                                                                  \
        W2;                                                                                     \
        __builtin_amdgcn_s_barrier();                                                           \
        __builtin_amdgcn_sched_barrier(0);                                                      \
        __builtin_amdgcn_s_setprio(1);                                                          \
        _Pragma("unroll")                                                                       \
        for (int nf = 0; nf < 10; ++nf) {                                                       \
            acc[0][nf + 10] = __builtin_amdgcn_mfma_f32_16x16x32_bf16(af0, bf[nf], acc[0][nf + 10], 0, 0, 0); \
            acc[1][nf + 10] = __builtin_amdgcn_mfma_f32_16x16x32_bf16(af1, bf[nf], acc[1][nf + 10], 0, 0, 0); \
        }                                                                                       \
        __builtin_amdgcn_s_setprio(0);                                                          \
    }                                                                                           \
    /* ---- p3: kstep1, nf 0-9 ; stage (TAU+2) A-kh0 ---- */                                    \
    {                                                                                           \
        af0 = *(const short8*)&a1k[addrA0];                                                     \
        af1 = *(const short8*)&a1k[addrA1];                                                     \
        short8 bf[10];                                                                          \
        _Pragma("unroll")                                                                       \
        for (int nf = 0; nf < 10; ++nf) bf[nf] = *(const short8*)&b1k[addrB + nf * 512];        \
        if (DO34) STAGE_A(A0s[cur_], ((TAU) + 2) * 64);                                         \
        LGKM0;                                                                                  \
        __builtin_amdgcn_s_barrier();                                                           \
        __builtin_amdgcn_sched_barrier(0);                                                      \
        __builtin_amdgcn_s_setprio(1);                                                          \
        _Pragma("unroll")                                                                       \
        for (int nf = 0; nf < 10; ++nf) {                                                       \
            acc[0][nf] = __builtin_amdgcn_mfma_f32_16x16x32_bf16(af0, bf[nf], acc[0][nf], 0, 0, 0); \
            acc[1][nf] = __builtin_amdgcn_mfma_f32_16x16x32_bf16(af1, bf[nf], acc[1][nf], 0, 0, 0); \
        }                                                                                       \
        __builtin_amdgcn_s_setprio(0);                                                          \
    }                                                                                           \
    /* ---- p4: kstep1, nf 10-19 ; stage (TAU+2) B-kh0 ; vmcnt ---- */                          \
    {                                                                                           \
        short8 bf[10];                                                                          \
        _Pragma("unroll")                                                                       \
        for (int nf = 0; nf < 10; ++nf) bf[nf] = *(const short8*)&b1k[addrB + (nf + 10) * 512]; \
        if (DO34) STAGE_B(B0s[cur_], ((TAU) + 2) * 64);                                         \
        LGKM0;                                                                                  \
        W4;                                                                                     \
        __builtin_amdgcn_s_barrier();                                                           \
        __builtin_amdgcn_sched_barrier(0);                                                      \
        __builtin_amdgcn_s_setprio(1);                                                          \
        _Pragma("unroll")                                                                       \
        for (int nf = 0; nf < 10; ++nf) {                                                       \
            acc[0][nf + 10] = __builtin_amdgcn_mfma_f32_16x16x32_bf16(af0, bf[nf], acc[0][nf + 10], 0, 0, 0); \
            acc[1][nf + 10] = __builtin_amdgcn_mfma_f32_16x16x32_bf16(af1, bf[nf], acc[1][nf + 10], 0, 0, 0); \
        }                                                                                       \
        __builtin_amdgcn_s_setprio(0);                                                          \
    }                                                                                           \
}

    #pragma unroll 2
    for (int tau = 0; tau < 30; ++tau)
        TILE_BODY(tau, 1, 1, VMW(8), VMW(8));
    TILE_BODY(30, 1, 0, VMW(8), VMW(4));
    TILE_BODY(31, 0, 0, VMW(0), ((void)0));

#undef TILE_BODY
#undef STAGE_A
#undef STAGE_B

    // ---- epilogue: RoPE (+1/64 q-scale) on q,k,q2,k2 head-groups; V transposed ----
    const int cr = (lane >> 4) * 4;
    const int cc = lane & 15;
    const int rw = row0 + w * 32;
    const float L2C = -0.41524101186092029f;  // -log2(10000)/32
    float inv0 = exp2f((float)cc * L2C);
    float inv1 = exp2f((float)(16 + cc) * L2C);

    #pragma unroll
    for (int hg = 0; hg < 5; ++hg) {
        const int cg = col0 + hg * 64;        // global column of this head group
        const int p  = cg >> 10;              // 0=q 1=k 2=q2 3=k2 4=v
        const int h  = (cg >> 6) & 15;
        if (p < 4) {
            const float sc = (p == 0 || p == 2) ? 0.015625f : 1.0f;
            #pragma unroll
            for (int m = 0; m < 2; ++m) {
                #pragma unroll
                for (int rr = 0; rr < 4; ++rr) {
                    int r = rw + m * 16 + cr + rr;
                    float tt = (float)(r & 2047);
                    float s0, c0, s1, c1;
                    __sincosf(tt * inv0, &s0, &c0);
                    __sincosf(tt * inv1, &s1, &c1);
                    float x1, x2;
                    x1 = acc[m][hg * 4 + 0][rr]; x2 = acc[m][hg * 4 + 2][rr];
                    acc[m][hg * 4 + 0][rr] = (x1 * c0 + x2 * s0) * sc;
                    acc[m][hg * 4 + 2][rr] = (x2 * c0 - x1 * s0) * sc;
                    x1 = acc[m][hg * 4 + 1][rr]; x2 = acc[m][hg * 4 + 3][rr];
                    acc[m][hg * 4 + 1][rr] = (x1 * c1 + x2 * s1) * sc;
                    acc[m][hg * 4 + 3][rr] = (x2 * c1 - x1 * s1) * sc;
                }
            }
            unsigned short* hp = Ch + (size_t)p * 4194304;
            #pragma unroll
            for (int m = 0; m < 2; ++m) {
                int r0  = rw + m * 16 + cr;
                int bhi = ((r0 >> 11) << 4) + h;
                size_t base = ((size_t)bhi * 2048 + (r0 & 2047)) * 64;
                #pragma unroll
                for (int j = 0; j < 4; ++j) {
                    int d = j * 16 + cc;
                    #pragma unroll
                    for (int rr = 0; rr < 4; ++rr)
                        hp[base + (size_t)rr * 64 + d] = f2bf(acc[m][hg * 4 + j][rr]);
                }
            }
        } else {
            #pragma unroll
            for (int m = 0; m < 2; ++m) {
                int r0  = rw + m * 16 + cr;
                int bhi = ((r0 >> 11) << 4) + h;
                #pragma unroll
                for (int j = 0; j < 4; ++j) {
                    int d = j * 16 + cc;
                    ushort4 o;
                    o.x = f2bf(acc[m][hg * 4 + j][0]); o.y = f2bf(acc[m][hg * 4 + j][1]);
                    o.z = f2bf(acc[m][hg * 4 + j][2]); o.w = f2bf(acc[m][hg * 4 + j][3]);
                    *(ushort4*)(Vt + ((size_t)bhi * 64 + d) * 2048 + (r0 & 2047)) = o;
                }
            }
        }
    }
}

// ---------------------------------------------------------------------------
// Output projection: C = (hiA+loA)*hiB^T + hiA*loB^T (3-term), fp32 out.
// Tile 128x64, grid (32,16)=512 blocks (2/CU), 24 KB LDS, wave-tile 64x32.
// ---------------------------------------------------------------------------
__global__ __launch_bounds__(256)
void gemm_proj(const unsigned short* __restrict__ Ap,
               const unsigned short* __restrict__ Bp,
               float* __restrict__ Cf)
{
    __shared__ __align__(16) unsigned short Ah[128 * 32];
    __shared__ __align__(16) unsigned short Al[128 * 32];
    __shared__ __align__(16) unsigned short Bh[64 * 32];
    __shared__ __align__(16) unsigned short Bl[64 * 32];

    const int t    = threadIdx.x;
    const int lane = t & 63;
    const int s    = lane & 15;
    const int row0 = blockIdx.x * 128;
    const int col0 = blockIdx.y * 64;
    const int m0   = ((t >> 6) >> 1) * 64;
    const int n0   = ((t >> 6) & 1) * 32;

    floatx4 acc[4][2];
    #pragma unroll
    for (int i = 0; i < 4; ++i)
        #pragma unroll
        for (int j = 0; j < 2; ++j)
            acc[i][j] = (floatx4)(0.0f);

    const int sr  = t >> 2;
    const int skx = ((t & 3) ^ ((t >> 3) & 3)) * 8;
    char* dA  = (char*)Ah + (size_t)t * 16;
    char* dAl = (char*)Al + (size_t)t * 16;
    char* dB  = (char*)Bh + (size_t)t * 16;
    char* dBl = (char*)Bl + (size_t)t * 16;
    const size_t arow = (size_t)(row0 + sr) * 2048 + skx;
    const size_t brow = (size_t)(col0 + sr) * 2048 + skx;   // sr in [0,64)

    #define ISSUE(k0)                                                                         \
    {                                                                                         \
        const unsigned short* ga = Ap + arow + (k0);                                          \
        const unsigned short* gb = Bp + brow + (k0);                                          \
        __builtin_amdgcn_global_load_lds((gvoid*)ga,                 (lvoid*)dA,          16, 0, 0); \
        __builtin_amdgcn_global_load_lds((gvoid*)(ga + 64*2048),     (lvoid*)(dA + 4096), 16, 0, 0); \
        __builtin_amdgcn_global_load_lds((gvoid*)(ga + 1024),        (lvoid*)dAl,         16, 0, 0); \
        __builtin_amdgcn_global_load_lds((gvoid*)(ga + 1024+64*2048),(lvoid*)(dAl + 4096),16, 0, 0); \
        __builtin_amdgcn_global_load_lds((gvoid*)gb,                 (lvoid*)dB,          16, 0, 0); \
        __builtin_amdgcn_global_load_lds((gvoid*)(gb + 1024),        (lvoid*)dBl,         16, 0, 0); \
    }

    const int cofs = (((lane >> 4) ^ ((lane >> 1) & 3)) << 3);

    ISSUE(0);
    for (int ks = 0; ks < 32; ++ks) {
        __syncthreads();
        short8 ahf[4], alf[4], bhf[2], blf[2];
        #pragma unroll
        for (int i = 0; i < 4; ++i) {
            int ra = (m0 + i * 16 + s) * 32 + cofs;
            ahf[i] = *(const short8*)&Ah[ra];
            alf[i] = *(const short8*)&Al[ra];
        }
        #pragma unroll
        for (int j = 0; j < 2; ++j) {
            int rb = (n0 + j * 16 + s) * 32 + cofs;
            bhf[j] = *(const short8*)&Bh[rb];
            blf[j] = *(const short8*)&Bl[rb];
        }
        #pragma unroll
        for (int i = 0; i < 4; ++i)
            #pragma unroll
            for (int j = 0; j < 2; ++j) {
                acc[i][j] = __builtin_amdgcn_mfma_f32_16x16x32_bf16(ahf[i], bhf[j], acc[i][j], 0, 0, 0);
                acc[i][j] = __builtin_amdgcn_mfma_f32_16x16x32_bf16(alf[i], bhf[j], acc[i][j], 0, 0, 0);
                acc[i][j] = __builtin_amdgcn_mfma_f32_16x16x32_bf16(ahf[i], blf[j], acc[i][j], 0, 0, 0);
            }
        __syncthreads();
        if (ks + 1 < 32) ISSUE((ks + 1) * 32);
    }
    #undef ISSUE

    const int cr = (lane >> 4) * 4;
    const int cc = lane & 15;
    #pragma unroll
    for (int i = 0; i < 4; ++i)
        #pragma unroll
        for (int j = 0; j < 2; ++j) {
            int r = row0 + m0 + i * 16 + cr;
            int c = col0 + n0 + j * 16 + cc;
            #pragma unroll
            for (int rr = 0; rr < 4; ++rr)
                Cf[(size_t)(r + rr) * 1024 + c] = acc[i][j][rr];
        }
}

// ---------------------------------------------------------------------------
// MFMA bilinear causal attention, S-transposed, q-frags hoisted to registers.
// psq overlays qs/q2s (dead after the one-time q-frag hoist) => 3 barriers/iter.
// LDS 80 KB, 2 blocks/CU.
// ---------------------------------------------------------------------------
__global__ __launch_bounds__(256, 2)
void attn_mfma(const unsigned short* __restrict__ qh, const unsigned short* __restrict__ q2h,
               const unsigned short* __restrict__ kh, const unsigned short* __restrict__ k2h,
               const unsigned short* __restrict__ vt, unsigned short* __restrict__ zout)
{
    __shared__ __align__(16) unsigned short smem[40960];   // 80 KB
    unsigned short* qs  = smem;              // [128][64] rot8 (init only)
    unsigned short* q2s = smem + 8192;
    unsigned short* psq = smem;              // [128][128] rot16, overlays qs/q2s
    unsigned short* ks  = smem + 16384;      // [128][64] rot8
    unsigned short* k2s = smem + 24576;
    unsigned short* vts = smem + 32768;      // [64][128] rot16

    const int bh = blockIdx.y;
    const int qt = (bh < 16) ? (15 - blockIdx.x) : blockIdx.x;  // pair heavy+light
    const int t  = threadIdx.x;
    const int lane = t & 63;
    const int w    = t >> 6;
    const int s    = lane & 15;
    const int g    = lane >> 4;
    const int m0   = (w >> 1) * 64;   // k-split
    const int n0   = (w & 1) * 64;    // q-split

    // ---- stage q, q2 once, then hoist frags to registers ----
    {
        const unsigned short* qb  = qh  + ((size_t)bh * 2048 + qt * 128) * 64;
        const unsigned short* q2b = q2h + ((size_t)bh * 2048 + qt * 128) * 64;
        const int row = t >> 1;
        #pragma unroll
        for (int c = 0; c < 4; ++c) {
            int cg  = (t & 1) * 4 + c;
            short8 a  = *(const short8*)(qb  + (size_t)row * 64 + cg * 8);
            short8 a2 = *(const short8*)(q2b + (size_t)row * 64 + cg * 8);
            int cgm = (cg + row) & 7;
            *(short8*)&qs [row * 64 + cgm * 8] = a;
            *(short8*)&q2s[row * 64 + cgm * 8] = a2;
        }
    }
    __syncthreads();
    short8 bq[2][4], bq2[2][4];
    #pragma unroll
    for (int kstep = 0; kstep < 2; ++kstep) {
        const int gl = kstep * 4 + g;
        #pragma unroll
        for (int j = 0; j < 4; ++j) {
            int row = n0 + j * 16 + s;
            int a = row * 64 + ((gl + row) & 7) * 8;
            bq[kstep][j]  = *(const short8*)&qs [a];
            bq2[kstep][j] = *(const short8*)&q2s[a];
        }
    }

    floatx4 zac[2][4];
    #pragma unroll
    for (int i = 0; i < 2; ++i)
        #pragma unroll
        for (int j = 0; j < 4; ++j)
            zac[i][j] = (floatx4)(0.0f);

    for (int tk = 0; tk <= qt; ++tk) {
        // ---- register prefetch ----
        short8 kf[4], k2f[4], vf[4];
        {
            const unsigned short* kb  = kh  + ((size_t)bh * 2048 + tk * 128) * 64;
            const unsigned short* k2b = k2h + ((size_t)bh * 2048 + tk * 128) * 64;
            const unsigned short* vb  = vt  + (size_t)bh * 131072 + tk * 128;
            const int krow = t >> 1;
            const int vd   = t >> 2;
            #pragma unroll
            for (int c = 0; c < 4; ++c) {
                int cg = (t & 1) * 4 + c;
                kf[c]  = *(const short8*)(kb  + (size_t)krow * 64 + cg * 8);
                k2f[c] = *(const short8*)(k2b + (size_t)krow * 64 + cg * 8);
                int cg16 = 4 * (t & 3) + c;
                vf[c]  = *(const short8*)(vb + (size_t)vd * 2048 + cg16 * 8);
            }
        }
        __syncthreads();   // b0: prev PV done (psq/vts); prev S done (ks/k2s); q-hoist done
        {
            const int krow = t >> 1;
            const int vd   = t >> 2;
            #pragma unroll
            for (int c = 0; c < 4; ++c) {
                int cg  = (t & 1) * 4 + c;
                int cgm = (cg + krow) & 7;
                *(short8*)&ks [krow * 64 + cgm * 8] = kf[c];
                *(short8*)&k2s[krow * 64 + cgm * 8] = k2f[c];
                int cg16  = 4 * (t & 3) + c;
                int cgm16 = (cg16 + vd) & 15;
                *(short8*)&vts[vd * 128 + cgm16 * 8] = vf[c];
            }
        }
        __syncthreads();   // b1: tiles visible

        // ---- S + P, i-outer (a1/a2 footprint = one i at a time) ----
        #pragma unroll
        for (int i = 0; i < 4; ++i) {
            floatx4 a1[4], a2[4];
            #pragma unroll
            for (int j = 0; j < 4; ++j) { a1[j] = (floatx4)(0.0f); a2[j] = (floatx4)(0.0f); }
            #pragma unroll
            for (int kstep = 0; kstep < 2; ++kstep) {
                const int gl = kstep * 4 + g;
                int row = m0 + i * 16 + s;
                int a = row * 64 + ((gl + row) & 7) * 8;
                short8 ak  = *(const short8*)&ks [a];
                short8 ak2 = *(const short8*)&k2s[a];
                #pragma unroll
                for (int j = 0; j < 4; ++j) {
                    a1[j] = __builtin_amdgcn_mfma_f32_16x16x32_bf16(ak,  bq[kstep][j],  a1[j], 0, 0, 0);
                    a2[j] = __builtin_amdgcn_mfma_f32_16x16x32_bf16(ak2, bq2[kstep][j], a2[j], 0, 0, 0);
                }
            }
            // P-write for this i: psq region unread by anyone during the loop
            const int kl0   = m0 + i * 16 + g * 4;
            const int chunk = kl0 >> 3;
            const int sub   = kl0 & 7;
            if (tk < qt) {
                #pragma unroll
                for (int j = 0; j < 4; ++j) {
                    const int ql = n0 + j * 16 + s;
                    ushort4 pw;
                    pw.x = f2bf(a1[j][0] * a2[j][0]);
                    pw.y = f2bf(a1[j][1] * a2[j][1]);
                    pw.z = f2bf(a1[j][2] * a2[j][2]);
                    pw.w = f2bf(a1[j][3] * a2[j][3]);
                    *(ushort4*)&psq[ql * 128 + ((chunk + ql) & 15) * 8 + sub] = pw;
                }
            } else {
                #pragma unroll
                for (int j = 0; j < 4; ++j) {
                    const int ql = n0 + j * 16 + s;
                    ushort4 pw;
                    pw.x = (kl0 + 0 <= ql) ? f2bf(a1[j][0] * a2[j][0]) : (unsigned short)0;
                    pw.y = (kl0 + 1 <= ql) ? f2bf(a1[j][1] * a2[j][1]) : (unsigned short)0;
                    pw.z = (kl0 + 2 <= ql) ? f2bf(a1[j][2] * a2[j][2]) : (unsigned short)0;
                    pw.w = (kl0 + 3 <= ql) ? f2bf(a1[j][3] * a2[j][3]) : (unsigned short)0;
                    *(ushort4*)&psq[ql * 128 + ((chunk + ql) & 15) * 8 + sub] = pw;
                }
            }
        }

        __syncthreads();   // b2: psq visible

        // ---- PV: z[q][d] += P[q][k] * vT[d][k] ----
        const int wm0 = w * 32;
        #pragma unroll
        for (int kstep = 0; kstep < 4; ++kstep) {
            const int cbase = kstep * 4 + g;
            short8 ap[2], bv[4];
            #pragma unroll
            for (int i2 = 0; i2 < 2; ++i2) {
                int q = wm0 + i2 * 16 + s;
                ap[i2] = *(const short8*)&psq[q * 128 + ((cbase + q) & 15) * 8];
            }
            #pragma unroll
            for (int jd = 0; jd < 4; ++jd) {
                int d = jd * 16 + s;
                bv[jd] = *(const short8*)&vts[d * 128 + ((cbase + d) & 15) * 8];
            }
            #pragma unroll
            for (int i2 = 0; i2 < 2; ++i2)
                #pragma unroll
                for (int jd = 0; jd < 4; ++jd)
                    zac[i2][jd] = __builtin_amdgcn_mfma_f32_16x16x32_bf16(ap[i2], bv[jd], zac[i2][jd], 0, 0, 0);
        }
    }

    // ---- epilogue: z -> split bf16 [hi | lo] into zout[4096][2048] ----
    const int b = bh >> 4, h = bh & 15;
    const size_t zrow0 = (size_t)(b * TSEQ + qt * 128);
    #pragma unroll
    for (int i2 = 0; i2 < 2; ++i2)
        #pragma unroll
        for (int j = 0; j < 4; ++j)
            #pragma unroll
            for (int r = 0; r < 4; ++r) {
                float zv = zac[i2][j][r];
                unsigned short hi = f2bf(zv);
                unsigned short lo = f2bf(zv - bf2f(hi));
                size_t row = zrow0 + w * 32 + i2 * 16 + g * 4 + r;
                int col = h * 64 + j * 16 + s;
                zout[row * 2048 + col]        = hi;
                zout[row * 2048 + 1024 + col] = lo;
            }
}

// ---------------------------------------------------------------------------
extern "C" void kernel_launch(void* const* d_in, const int* in_sizes, int n_in,
                              void* d_out, int out_size, void* d_ws, size_t ws_size,
                              hipStream_t stream)
{
    const float* x     = (const float*)d_in[0];
    const float* Wq    = (const float*)d_in[1];
    const float* Wk    = (const float*)d_in[2];
    const float* Wq2   = (const float*)d_in[3];
    const float* Wk2   = (const float*)d_in[4];
    const float* Wv    = (const float*)d_in[5];
    const float* Wproj = (const float*)d_in[6];

    // workspace (bytes):
    //   Xp    bf16 [4096][2048] (x-split, later z-split) @ 0          (16,777,216)
    //   Wp    bf16 [6144][2048]                          @ 16,777,216 (25,165,824)
    //         rows [0,1024)    = Wproj [hi|lo]
    //         rows [1024,6144) = Wq,Wk,Wq2,Wk2,Wv [hi|hi] (duplicated)
    //   heads bf16 4x[32][2048][64] (q,k,q2,k2)          @ 41,943,040 (33,554,432)
    //   vt    bf16 [32][64][2048]                        @ 75,497,472 ( 8,388,608)
    unsigned short* Xp    = (unsigned short*)d_ws;
    unsigned short* Wp    = (unsigned short*)((char*)d_ws + 16777216);
    unsigned short* heads = (unsigned short*)((char*)d_ws + 41943040);
    unsigned short* vt    = (unsigned short*)((char*)d_ws + 75497472);

    const size_t HS = (size_t)32 * 2048 * 64;
    unsigned short* qh  = heads;
    unsigned short* kh  = heads + 1 * HS;
    unsigned short* q2h = heads + 2 * HS;
    unsigned short* k2h = heads + 3 * HS;

    pack_all_kernel<<<10240, 256, 0, stream>>>(x, Wproj, Wq, Wk, Wq2, Wk2, Wv, Xp, Wp);
    gemm_qkv<<<dim3(16, 16), 512, 0, stream>>>(Xp, Wp + (size_t)1024 * 2048, heads, vt);
    attn_mfma<<<dim3(16, 32), 256, 0, stream>>>(qh, q2h, kh, k2h, vt, Xp);
    gemm_proj<<<dim3(32, 16), 256, 0, stream>>>(Xp, Wp, (float*)d_out);
}